// Round 10
// baseline (80.121 us; speedup 1.0000x reference)
//
#include <hip/hip_runtime.h>
#include <float.h>

// ROI adaptive max-pool 7x7. features [512,64,64] fp32, 1024 ROIs.
// Phase 1: transpose features to [H][W][C] in d_ws, block id = bs*8+bc so
//   channel-chunk bc is WRITTEN by XCD bc (blockIdx round-robins XCDs).
//   Feature reads are non-temporal (read-once); ft write stays cached.
// Phase 2: pool; block id = g*8+bc, 4 waves = 4 ROIs x the SAME 64-channel
//   chunk bc -> every ft read hits the local XCD L2 (R9-proven, +3us).
//   Output stores are NON-TEMPORAL: the 100 MB out stream is never re-read,
//   so it must not evict the 1 MB ft slice from L2. __launch_bounds__(256,6)
//   targets 6 waves/SIMD (VGPR <= 85) so store bursts tile the timeline.
// Row loop/epilogue otherwise byte-identical to the R6/R9 champion.
constexpr int CC = 512, HH = 64, WW = 64, HW = HH * WW;
#define NEG (-FLT_MAX)
typedef float f4 __attribute__((ext_vector_type(4)));

// ---------- phase 1: [C][HW] -> [HW][C], XCD-keyed by channel chunk ----------
__global__ __launch_bounds__(256) void transpose_kernel(
    const float* __restrict__ f, float* __restrict__ ft)
{
    __shared__ float tile[64][65];
    int bc = blockIdx.x & 7;             // channel chunk -> XCD bc
    int bs = blockIdx.x >> 3;            // hw tile (4096/64)
    int tx = threadIdx.x & 63, ty0 = threadIdx.x >> 6;
#pragma unroll
    for (int k = 0; k < 16; ++k) {
        int c = k * 4 + ty0;
        tile[c][tx] = __builtin_nontemporal_load(
            &f[(size_t)(bc * 64 + c) * HW + bs * 64 + tx]);          // read-once
    }
    __syncthreads();
#pragma unroll
    for (int k = 0; k < 16; ++k) {
        int s = k * 4 + ty0;
        ft[(size_t)(bs * 64 + s) * CC + bc * 64 + tx] = tile[tx][s]; // cached: pool re-reads
    }
}

// static per-bin cell ranges: bin j only touches cells
// k in [floor(2j/7), ceil(9(j+1)/7)) for w_len in [2,9] -> 36 terms total.
#define KMIN(j) ((2 * (j)) / 7)
#define KMAX(j) ((9 * ((j) + 1) + 6) / 7)

// ---------- phase 2: pool from [HW][C], reading only chunk bc ----------
__global__ __launch_bounds__(256, 6) void pool_kernel(
    const float* __restrict__ ft,        // [H][W][C]
    const int4*  __restrict__ rois,      // [R] (x1,y1,x2,y2) image px
    float* __restrict__ out,             // [R,C,7,7]
    int nblocks)
{
    __shared__ __align__(16) float lds[4][32 * 49];
    int wslot = threadIdx.x >> 6;
    int b = __builtin_amdgcn_readfirstlane(blockIdx.x);
    if (b >= nblocks) return;
    int lane = threadIdx.x & 63;

    int bc = b & 7;                      // channel chunk == this XCD
    int g  = b >> 3;                     // ROI group (4 ROIs per block)
    int r  = g * 4 + wslot;              // this wave's ROI
    int c0 = bc << 6;                    // 64-channel chunk base

    int4 roi = rois[r];                  // uniform -> s_load
    // (px * 1/16.f) truncated == px >> 4 for px in [0,1024): exact in fp32.
    int x1 = roi.x >> 4, y1 = roi.y >> 4, x2 = roi.z >> 4, y2 = roi.w >> 4;
    int hl = y2 - y1 + 1, wl = x2 - x1 + 1;   // 2..9 each (bw,bh >= 16 px)

    // torch adaptive bins (uniform -> SGPR): [floor(i*L/7), ceil((i+1)*L/7)).
    int hs[7], he[7], s_[7], e_[7];
#pragma unroll
    for (int i = 0; i < 7; ++i) {
        hs[i] = y1 + (i * hl) / 7;
        he[i] = y1 + ((i + 1) * hl + 6) / 7;
        s_[i] = (i * wl) / 7;                 // cell index relative to x1
        e_[i] = ((i + 1) * wl + 6) / 7;
    }

    float acc[7][7];
#pragma unroll
    for (int i = 0; i < 7; ++i)
#pragma unroll
        for (int j = 0; j < 7; ++j) acc[i][j] = NEG;

    const float* fb = ft + c0 + lane;
    for (int h = y1; h <= y2; ++h) {     // uniform, 2..9 iters
        const float* rowp = fb + (size_t)h * (WW * CC);
        float v[9];
#pragma unroll
        for (int k = 0; k < 9; ++k) {
            v[k] = NEG;
            if (k < wl)                  // uniform scalar branch, avg ~5 loads
                v[k] = rowp[(x1 + k) * CC];
        }
        float m[7];
#pragma unroll
        for (int j = 0; j < 7; ++j) {    // 36 uniform-predicated terms
            float a = NEG;
#pragma unroll
            for (int k = KMIN(j); k < KMAX(j); ++k) {
                bool p = (k >= s_[j]) && (k < e_[j]);   // uniform
                a = fmaxf(a, p ? v[k] : NEG);
            }
            m[j] = a;
        }
#pragma unroll
        for (int i = 0; i < 7; ++i) {
            if (h >= hs[i] && h < he[i]) {        // uniform scalar branch
#pragma unroll
                for (int j = 0; j < 7; ++j)
                    acc[i][j] = fmaxf(acc[i][j], m[j]);
            }
        }
    }

    // Store: transpose [64ch][49] -> flat [c][bin] via LDS, 2 rounds of 32ch.
    float* L  = lds[wslot];
    float* ob = out + ((size_t)r * CC + c0) * 49;
#pragma unroll
    for (int round = 0; round < 2; ++round) {
        if ((lane >> 5) == round) {
            float* p = L + (lane & 31) * 49;      // stride 49 (odd): conflict-free
#pragma unroll
            for (int i = 0; i < 7; ++i)
#pragma unroll
                for (int j = 0; j < 7; ++j) p[i * 7 + j] = acc[i][j];
        }
        asm volatile("s_waitcnt lgkmcnt(0)" ::: "memory");
        float* og = ob + round * 1568;            // 1568 floats contiguous
#pragma unroll
        for (int s = 0; s < 6; ++s) {             // 6 x (64 lanes x dwordx4)
            int idx = s * 64 + lane;
            __builtin_nontemporal_store(*(const f4*)(L + idx * 4),
                                        (f4*)(og + idx * 4));
        }
        if (lane < 8) {                           // 392 = 6*64 + 8 tail
            int idx = 384 + lane;
            __builtin_nontemporal_store(*(const f4*)(L + idx * 4),
                                        (f4*)(og + idx * 4));
        }
        asm volatile("s_waitcnt lgkmcnt(0)" ::: "memory"); // reads done before re-write
    }
}

// ---------- fallback (R4, proven): used only if ws_size < 8 MB ----------
__global__ __launch_bounds__(256) void roi_pool_direct(
    const float* __restrict__ features, const int4* __restrict__ rois,
    float* __restrict__ out, int ngroups)
{
    int wid = __builtin_amdgcn_readfirstlane(
        blockIdx.x * (blockDim.x >> 6) + (threadIdx.x >> 6));
    if (wid >= ngroups) return;
    int lane = threadIdx.x & 63;
    if (lane >= 49) return;
    int r = wid >> 4, c0 = (wid & 15) * 32;
    int4 roi = rois[r];
    int x1 = roi.x >> 4, y1 = roi.y >> 4, x2 = roi.z >> 4, y2 = roi.w >> 4;
    int h_len = y2 - y1 + 1, w_len = x2 - x1 + 1;
    int oh = lane / 7, ow = lane - oh * 7;
    int hs = y1 + (oh * h_len) / 7, he = y1 + ((oh + 1) * h_len + 6) / 7;
    int ws = x1 + (ow * w_len) / 7, we = x1 + ((ow + 1) * w_len + 6) / 7;
    int wlst = we - 1;
    int wa = ws, wb = min(ws + 1, wlst), wc = min(ws + 2, wlst);
    bool need1 = hs + 1 < he, need2 = hs + 2 < he;
    int o0 = (hs * WW + wa) * 4, o0b = (hs * WW + wb) * 4, o0c = (hs * WW + wc) * 4;
    const char* fb = (const char*)features + (size_t)c0 * (HW * 4);
    float* ob = out + ((size_t)r * CC + c0) * 49 + lane;
#pragma unroll 4
    for (int j = 0; j < 32; ++j) {
        float a = fmaxf(fmaxf(*(const float*)(fb + o0),
                              *(const float*)(fb + o0b)),
                        *(const float*)(fb + o0c));
        if (need1) {
            a = fmaxf(a, fmaxf(fmaxf(*(const float*)(fb + o0 + WW * 4),
                                     *(const float*)(fb + o0b + WW * 4)),
                               *(const float*)(fb + o0c + WW * 4)));
        }
        if (need2) {
            a = fmaxf(a, fmaxf(fmaxf(*(const float*)(fb + o0 + 2 * WW * 4),
                                     *(const float*)(fb + o0b + 2 * WW * 4)),
                               *(const float*)(fb + o0c + 2 * WW * 4)));
        }
        *ob = a;
        fb += HW * 4;
        ob += 49;
    }
}

extern "C" void kernel_launch(void* const* d_in, const int* in_sizes, int n_in,
                              void* d_out, int out_size, void* d_ws, size_t ws_size,
                              hipStream_t stream) {
    const float* features = (const float*)d_in[0];   // [1,512,64,64] fp32
    const int4*  rois     = (const int4*)d_in[1];    // [R,4] int32
    float* out = (float*)d_out;
    int R = out_size / (CC * 49);                    // 1024

    if (ws_size >= (size_t)CC * HW * sizeof(float)) {
        float* ft = (float*)d_ws;                    // [HW][C], 8 MB
        transpose_kernel<<<512, 256, 0, stream>>>(features, ft);
        int nblocks = (R / 4) * 8;                   // g*8 + bc, 2048 blocks
        pool_kernel<<<nblocks, 256, 0, stream>>>(ft, rois, out, nblocks);
    } else {
        int ngroups = R * 16;
        roi_pool_direct<<<(ngroups + 3) / 4, 256, 0, stream>>>(features, rois, out, ngroups);
    }
}

// Round 11
// 33.805 us; speedup vs baseline: 2.3701x; 2.3701x over previous
//
#include <hip/hip_runtime.h>
#include <float.h>

// ROI adaptive max-pool 7x7. features [512,64,64] fp32, 1024 ROIs.
// == R9 champion (36.9us) + EXACTLY ONE delta: non-temporal output stores
// (and nt-load of the read-once features in the transpose). NO launch_bounds
// occupancy cap (R10's (256,6) forced VGPR=40 -> 65MB of scratch spills).
// Phase 1: transpose features to [H][W][C] in d_ws, block id = bs*8+bc so
//   channel-chunk bc is WRITTEN by XCD bc (blockIdx round-robins XCDs).
// Phase 2: pool; block id = g*8+bc, 4 waves = 4 ROIs x the SAME 64-channel
//   chunk bc -> ft reads hit the local XCD L2 (R9-proven). Out stores are
//   non-temporal: the 100 MB out stream is never re-read and must not evict
//   the 1 MB ft slice from L2.
constexpr int CC = 512, HH = 64, WW = 64, HW = HH * WW;
#define NEG (-FLT_MAX)
typedef float f4 __attribute__((ext_vector_type(4)));

// ---------- phase 1: [C][HW] -> [HW][C], XCD-keyed by channel chunk ----------
__global__ __launch_bounds__(256) void transpose_kernel(
    const float* __restrict__ f, float* __restrict__ ft)
{
    __shared__ float tile[64][65];
    int bc = blockIdx.x & 7;             // channel chunk -> XCD bc
    int bs = blockIdx.x >> 3;            // hw tile (4096/64)
    int tx = threadIdx.x & 63, ty0 = threadIdx.x >> 6;
#pragma unroll
    for (int k = 0; k < 16; ++k) {
        int c = k * 4 + ty0;
        tile[c][tx] = __builtin_nontemporal_load(
            &f[(size_t)(bc * 64 + c) * HW + bs * 64 + tx]);          // read-once
    }
    __syncthreads();
#pragma unroll
    for (int k = 0; k < 16; ++k) {
        int s = k * 4 + ty0;
        ft[(size_t)(bs * 64 + s) * CC + bc * 64 + tx] = tile[tx][s]; // cached: pool re-reads
    }
}

// static per-bin cell ranges: bin j only touches cells
// k in [floor(2j/7), ceil(9(j+1)/7)) for w_len in [2,9] -> 36 terms total.
#define KMIN(j) ((2 * (j)) / 7)
#define KMAX(j) ((9 * ((j) + 1) + 6) / 7)

// ---------- phase 2: pool from [HW][C], reading only chunk bc ----------
__global__ __launch_bounds__(256) void pool_kernel(
    const float* __restrict__ ft,        // [H][W][C]
    const int4*  __restrict__ rois,      // [R] (x1,y1,x2,y2) image px
    float* __restrict__ out,             // [R,C,7,7]
    int nblocks)
{
    __shared__ __align__(16) float lds[4][32 * 49];
    int wslot = threadIdx.x >> 6;
    int b = __builtin_amdgcn_readfirstlane(blockIdx.x);
    if (b >= nblocks) return;
    int lane = threadIdx.x & 63;

    int bc = b & 7;                      // channel chunk == this XCD
    int g  = b >> 3;                     // ROI group (4 ROIs per block)
    int r  = g * 4 + wslot;              // this wave's ROI
    int c0 = bc << 6;                    // 64-channel chunk base

    int4 roi = rois[r];                  // uniform -> s_load
    // (px * 1/16.f) truncated == px >> 4 for px in [0,1024): exact in fp32.
    int x1 = roi.x >> 4, y1 = roi.y >> 4, x2 = roi.z >> 4, y2 = roi.w >> 4;
    int hl = y2 - y1 + 1, wl = x2 - x1 + 1;   // 2..9 each (bw,bh >= 16 px)

    // torch adaptive bins (uniform -> SGPR): [floor(i*L/7), ceil((i+1)*L/7)).
    int hs[7], he[7], s_[7], e_[7];
#pragma unroll
    for (int i = 0; i < 7; ++i) {
        hs[i] = y1 + (i * hl) / 7;
        he[i] = y1 + ((i + 1) * hl + 6) / 7;
        s_[i] = (i * wl) / 7;                 // cell index relative to x1
        e_[i] = ((i + 1) * wl + 6) / 7;
    }

    float acc[7][7];
#pragma unroll
    for (int i = 0; i < 7; ++i)
#pragma unroll
        for (int j = 0; j < 7; ++j) acc[i][j] = NEG;

    const float* fb = ft + c0 + lane;
    for (int h = y1; h <= y2; ++h) {     // uniform, 2..9 iters
        const float* rowp = fb + (size_t)h * (WW * CC);
        float v[9];
#pragma unroll
        for (int k = 0; k < 9; ++k) {
            v[k] = NEG;
            if (k < wl)                  // uniform scalar branch, avg ~5 loads
                v[k] = rowp[(x1 + k) * CC];
        }
        float m[7];
#pragma unroll
        for (int j = 0; j < 7; ++j) {    // 36 uniform-predicated terms
            float a = NEG;
#pragma unroll
            for (int k = KMIN(j); k < KMAX(j); ++k) {
                bool p = (k >= s_[j]) && (k < e_[j]);   // uniform
                a = fmaxf(a, p ? v[k] : NEG);
            }
            m[j] = a;
        }
#pragma unroll
        for (int i = 0; i < 7; ++i) {
            if (h >= hs[i] && h < he[i]) {        // uniform scalar branch
#pragma unroll
                for (int j = 0; j < 7; ++j)
                    acc[i][j] = fmaxf(acc[i][j], m[j]);
            }
        }
    }

    // Store: transpose [64ch][49] -> flat [c][bin] via LDS, 2 rounds of 32ch.
    float* L  = lds[wslot];
    float* ob = out + ((size_t)r * CC + c0) * 49;
#pragma unroll
    for (int round = 0; round < 2; ++round) {
        if ((lane >> 5) == round) {
            float* p = L + (lane & 31) * 49;      // stride 49 (odd): conflict-free
#pragma unroll
            for (int i = 0; i < 7; ++i)
#pragma unroll
                for (int j = 0; j < 7; ++j) p[i * 7 + j] = acc[i][j];
        }
        asm volatile("s_waitcnt lgkmcnt(0)" ::: "memory");
        float* og = ob + round * 1568;            // 1568 floats contiguous
#pragma unroll
        for (int s = 0; s < 6; ++s) {             // 6 x (64 lanes x dwordx4)
            int idx = s * 64 + lane;
            __builtin_nontemporal_store(*(const f4*)(L + idx * 4),
                                        (f4*)(og + idx * 4));
        }
        if (lane < 8) {                           // 392 = 6*64 + 8 tail
            int idx = 384 + lane;
            __builtin_nontemporal_store(*(const f4*)(L + idx * 4),
                                        (f4*)(og + idx * 4));
        }
        asm volatile("s_waitcnt lgkmcnt(0)" ::: "memory"); // reads done before re-write
    }
}

// ---------- fallback (R4, proven): used only if ws_size < 8 MB ----------
__global__ __launch_bounds__(256) void roi_pool_direct(
    const float* __restrict__ features, const int4* __restrict__ rois,
    float* __restrict__ out, int ngroups)
{
    int wid = __builtin_amdgcn_readfirstlane(
        blockIdx.x * (blockDim.x >> 6) + (threadIdx.x >> 6));
    if (wid >= ngroups) return;
    int lane = threadIdx.x & 63;
    if (lane >= 49) return;
    int r = wid >> 4, c0 = (wid & 15) * 32;
    int4 roi = rois[r];
    int x1 = roi.x >> 4, y1 = roi.y >> 4, x2 = roi.z >> 4, y2 = roi.w >> 4;
    int h_len = y2 - y1 + 1, w_len = x2 - x1 + 1;
    int oh = lane / 7, ow = lane - oh * 7;
    int hs = y1 + (oh * h_len) / 7, he = y1 + ((oh + 1) * h_len + 6) / 7;
    int ws = x1 + (ow * w_len) / 7, we = x1 + ((ow + 1) * w_len + 6) / 7;
    int wlst = we - 1;
    int wa = ws, wb = min(ws + 1, wlst), wc = min(ws + 2, wlst);
    bool need1 = hs + 1 < he, need2 = hs + 2 < he;
    int o0 = (hs * WW + wa) * 4, o0b = (hs * WW + wb) * 4, o0c = (hs * WW + wc) * 4;
    const char* fb = (const char*)features + (size_t)c0 * (HW * 4);
    float* ob = out + ((size_t)r * CC + c0) * 49 + lane;
#pragma unroll 4
    for (int j = 0; j < 32; ++j) {
        float a = fmaxf(fmaxf(*(const float*)(fb + o0),
                              *(const float*)(fb + o0b)),
                        *(const float*)(fb + o0c));
        if (need1) {
            a = fmaxf(a, fmaxf(fmaxf(*(const float*)(fb + o0 + WW * 4),
                                     *(const float*)(fb + o0b + WW * 4)),
                               *(const float*)(fb + o0c + WW * 4)));
        }
        if (need2) {
            a = fmaxf(a, fmaxf(fmaxf(*(const float*)(fb + o0 + 2 * WW * 4),
                                     *(const float*)(fb + o0b + 2 * WW * 4)),
                               *(const float*)(fb + o0c + 2 * WW * 4)));
        }
        *ob = a;
        fb += HW * 4;
        ob += 49;
    }
}

extern "C" void kernel_launch(void* const* d_in, const int* in_sizes, int n_in,
                              void* d_out, int out_size, void* d_ws, size_t ws_size,
                              hipStream_t stream) {
    const float* features = (const float*)d_in[0];   // [1,512,64,64] fp32
    const int4*  rois     = (const int4*)d_in[1];    // [R,4] int32
    float* out = (float*)d_out;
    int R = out_size / (CC * 49);                    // 1024

    if (ws_size >= (size_t)CC * HW * sizeof(float)) {
        float* ft = (float*)d_ws;                    // [HW][C], 8 MB
        transpose_kernel<<<512, 256, 0, stream>>>(features, ft);
        int nblocks = (R / 4) * 8;                   // g*8 + bc, 2048 blocks
        pool_kernel<<<nblocks, 256, 0, stream>>>(ft, rois, out, nblocks);
    } else {
        int ngroups = R * 16;
        roi_pool_direct<<<(ngroups + 3) / 4, 256, 0, stream>>>(features, rois, out, ngroups);
    }
}